// Round 2
// baseline (415.695 us; speedup 1.0000x reference)
//
#include <hip/hip_runtime.h>

// EdgeClassifier: out[e] = W2 . relu(W1 . concat(z_drug[row[e]], z_protein[col[e]]) + b1) + b2
// Pass 1: convert z tables fp32->bf16 into ws.
// Pass 2: tiled bf16 MFMA GEMM [64 edges x 256] x [256 x 128], fused layer-2 epilogue.
// Pipeline: double-buffered LDS, global_load_lds(16B) gather with pre-swizzled source.

typedef __attribute__((ext_vector_type(8))) short bhalf8;   // 8 x bf16
typedef __attribute__((ext_vector_type(4))) float f32x4;

#define TE 64   // edges per tile

__device__ __forceinline__ unsigned bfr(float f) {
    // fp32 -> bf16 bits, round-to-nearest-even
    unsigned u = __builtin_bit_cast(unsigned, f);
    return (u + 0x7fffu + ((u >> 16) & 1u)) >> 16;
}
__device__ __forceinline__ unsigned pk2(float a, float b) {
    return bfr(a) | (bfr(b) << 16);
}

__device__ __forceinline__ void gload_lds16(const void* g, void* l) {
    __builtin_amdgcn_global_load_lds(
        (const __attribute__((address_space(1))) void*)g,
        (__attribute__((address_space(3))) void*)l, 16, 0, 0);
}

// ---------- pass 1: fp32 -> bf16 table convert ----------
__global__ __launch_bounds__(256) void cvt_kernel(
    const float* __restrict__ a, const float* __restrict__ b,
    unsigned short* __restrict__ oa, unsigned short* __restrict__ ob,
    int na8, int nb8)
{
    int i = blockIdx.x * 256 + threadIdx.x;
    const float* src; unsigned short* dst; int j;
    if (i < na8) { src = a; dst = oa; j = i; }
    else if (i < na8 + nb8) { src = b; dst = ob; j = i - na8; }
    else return;
    const float4* s4 = (const float4*)src + (size_t)j * 2;
    float4 p = s4[0], q = s4[1];
    uint4 o;
    o.x = pk2(p.x, p.y); o.y = pk2(p.z, p.w);
    o.z = pk2(q.x, q.y); o.w = pk2(q.z, q.w);
    ((uint4*)dst)[j] = o;
}

// ---------- pass 2: main fused kernel ----------
__global__ __launch_bounds__(512, 4) void ec2_kernel(
    const unsigned short* __restrict__ zdb, const unsigned short* __restrict__ zpb,
    const int* __restrict__ eli, const float* __restrict__ W1,
    const float* __restrict__ b1, const float* __restrict__ W2,
    const float* __restrict__ b2, float* __restrict__ out,
    int E, int nTiles)
{
    // Z tiles in bf16, [TE][256] each, logically XOR-swizzled: chunk c holds src chunk c^(row&7)
    __shared__ __align__(16) short sZ[2][TE * 256];   // 2 x 32 KB
    __shared__ float sPart[8][TE];                    // 2 KB

    const int tid  = threadIdx.x;
    const int wave = tid >> 6;
    const int lane = tid & 63;
    const int l15  = lane & 15;
    const int lhi  = lane >> 4;        // 0..3

    // per-block: wave's W1 col-tile as bf16 B-fragments (cols wave*16 + l15)
    const int ocol = wave * 16 + l15;
    bhalf8 bfrag[8];
    #pragma unroll
    for (int ks = 0; ks < 8; ++ks) {
        const int k0 = ks * 32 + lhi * 8;
        const float4* src = (const float4*)(W1 + ocol * 256 + k0);
        float4 p = src[0], q = src[1];
        bhalf8 f;
        f[0] = (short)bfr(p.x); f[1] = (short)bfr(p.y);
        f[2] = (short)bfr(p.z); f[3] = (short)bfr(p.w);
        f[4] = (short)bfr(q.x); f[5] = (short)bfr(q.y);
        f[6] = (short)bfr(q.z); f[7] = (short)bfr(q.w);
        bfrag[ks] = f;
    }
    const float b1v = b1[ocol];
    const float w2v = W2[ocol];
    const float b2v = b2[0];

    // staging lane mapping: each wave stages rows wave*8 .. wave*8+7, 2 rows/instr
    const int stRow = lane >> 5;          // 0/1 within row pair
    const int halfS = (lane >> 4) & 1;    // 0 = drug half, 1 = protein half
    const int c15   = lane & 15;          // 16B chunk within the 256B half

    const int t0 = blockIdx.x;
    if (t0 >= nTiles) return;
    const int stride = gridDim.x;

    // prologue: stage tile t0 into buf0; prefetch indices for t0+stride
    int idxB[4];   // indices for the NEXT tile to stage
    {
        int idxA[4];
        #pragma unroll
        for (int it = 0; it < 4; ++it) {
            int r = wave * 8 + it * 2 + stRow;
            idxA[it] = eli[(size_t)halfS * E + t0 * TE + r];
        }
        #pragma unroll
        for (int it = 0; it < 4; ++it) {
            int row = wave * 8 + it * 2 + stRow;
            int sc  = c15 ^ (row & 7);
            const unsigned short* src =
                (halfS ? zpb : zdb) + (size_t)idxA[it] * 128 + sc * 8;
            short* dst = &sZ[0][(wave * 8 + it * 2) * 256];   // wave-uniform
            gload_lds16(src, dst);
        }
        int t1 = t0 + stride;
        if (t1 < nTiles) {
            #pragma unroll
            for (int it = 0; it < 4; ++it) {
                int r = wave * 8 + it * 2 + stRow;
                idxB[it] = eli[(size_t)halfS * E + t1 * TE + r];
            }
        }
    }

    int cur = 0;
    for (int t = t0; t < nTiles; t += stride) {
        const int tn  = t + stride;
        const int tn2 = tn + stride;

        __syncthreads();   // drains vmcnt: buf[cur] fully staged; sPart consumed

        // issue next tile's gathers into the other buffer (hides under MFMA+epilogue)
        if (tn < nTiles) {
            #pragma unroll
            for (int it = 0; it < 4; ++it) {
                int row = wave * 8 + it * 2 + stRow;
                int sc  = c15 ^ (row & 7);
                const unsigned short* src =
                    (halfS ? zpb : zdb) + (size_t)idxB[it] * 128 + sc * 8;
                short* dst = &sZ[cur ^ 1][(wave * 8 + it * 2) * 256];
                gload_lds16(src, dst);
            }
        }
        // prefetch indices two tiles ahead
        int idxC[4] = {0, 0, 0, 0};
        if (tn2 < nTiles) {
            #pragma unroll
            for (int it = 0; it < 4; ++it) {
                int r = wave * 8 + it * 2 + stRow;
                idxC[it] = eli[(size_t)halfS * E + tn2 * TE + r];
            }
        }

        // ---- MFMA: 4 row-tiles x 8 K-steps on buf[cur] ----
        f32x4 acc[4] = {{0.f,0.f,0.f,0.f},{0.f,0.f,0.f,0.f},
                        {0.f,0.f,0.f,0.f},{0.f,0.f,0.f,0.f}};
        const char* zbase = (const char*)sZ[cur];
        #pragma unroll
        for (int ks = 0; ks < 8; ++ks) {
            const int kb = ks * 64 + lhi * 16;
            #pragma unroll
            for (int rt = 0; rt < 4; ++rt) {
                const int row = rt * 16 + l15;
                int byte = (row * 512 + kb) ^ ((row & 7) << 4);
                bhalf8 af = *(const bhalf8*)(zbase + byte);
                acc[rt] = __builtin_amdgcn_mfma_f32_16x16x32_bf16(af, bfrag[ks], acc[rt], 0, 0, 0);
            }
        }

        // ---- epilogue: +b1, relu, *w2, butterfly 16-value x 16-lane reduce ----
        float v[16];
        #pragma unroll
        for (int rt = 0; rt < 4; ++rt)
            #pragma unroll
            for (int i = 0; i < 4; ++i)
                v[rt * 4 + i] = fmaxf(acc[rt][i] + b1v, 0.0f) * w2v;

        #pragma unroll
        for (int m = 1, cnt = 16; cnt > 1; m <<= 1, cnt >>= 1) {
            #pragma unroll
            for (int i = 0; i < 8; ++i) {
                if (i < cnt / 2) {
                    const bool hi = (l15 & m) != 0;
                    float snd = hi ? v[i] : v[i + cnt / 2];
                    float kp  = hi ? v[i + cnt / 2] : v[i];
                    v[i] = kp + __shfl_xor(snd, m, 64);
                }
            }
        }
        // lane l15 now holds total of value j = bitrev4(l15)
        {
            int j = ((l15 & 1) << 3) | ((l15 & 2) << 1) | ((l15 & 4) >> 1) | ((l15 & 8) >> 3);
            int orow = ((j >> 2) << 4) + lhi * 4 + (j & 3);
            sPart[wave][orow] = v[0];
        }
        __syncthreads();
        if (tid < TE) {
            const int eg = t * TE + tid;
            if (eg < E) {
                float s = b2v;
                #pragma unroll
                for (int w = 0; w < 8; ++w) s += sPart[w][tid];
                out[eg] = s;
            }
        }

        #pragma unroll
        for (int q = 0; q < 4; ++q) idxB[q] = idxC[q];
        cur ^= 1;
    }
}

// ---------- fallback (round-1 kernel, fp32 gather) if ws too small ----------
__global__ __launch_bounds__(512, 4) void ec_fallback(
    const float* __restrict__ zd, const float* __restrict__ zp,
    const int* __restrict__ eli, const float* __restrict__ W1,
    const float* __restrict__ b1, const float* __restrict__ W2,
    const float* __restrict__ b2, float* __restrict__ out,
    int E, int nTiles)
{
    __shared__ __align__(16) short sZ[TE * 256];
    __shared__ float sPart[8][TE];
    const int tid  = threadIdx.x;
    const int wave = tid >> 6;
    const int lane = tid & 63;
    const int l15  = lane & 15;
    const int lhi  = lane >> 4;
    const int ocol = wave * 16 + l15;
    bhalf8 bfrag[8];
    #pragma unroll
    for (int ks = 0; ks < 8; ++ks) {
        const int k0 = ks * 32 + lhi * 8;
        const float4* src = (const float4*)(W1 + ocol * 256 + k0);
        float4 p = src[0], q = src[1];
        bhalf8 f;
        f[0] = (short)bfr(p.x); f[1] = (short)bfr(p.y);
        f[2] = (short)bfr(p.z); f[3] = (short)bfr(p.w);
        f[4] = (short)bfr(q.x); f[5] = (short)bfr(q.y);
        f[6] = (short)bfr(q.z); f[7] = (short)bfr(q.w);
        bfrag[ks] = f;
    }
    const float b1v = b1[ocol];
    const float w2v = W2[ocol];
    const float b2v = b2[0];
    const int slot = tid >> 5;
    const int lane32 = tid & 31;
    for (int tile = blockIdx.x; tile < nTiles; tile += gridDim.x) {
        const int base = tile * TE;
        __syncthreads();
        #pragma unroll
        for (int r = 0; r < 4; ++r) {
            const int e  = slot * 4 + r;
            const int eg = base + e;
            int drow = 0, pcol = 0;
            if (eg < E) { drow = eli[eg]; pcol = eli[E + eg]; }
            float4 v = ((const float4*)(zd + (size_t)drow * 128))[lane32];
            float4 u = ((const float4*)(zp + (size_t)pcol * 128))[lane32];
            int byte0 = (e * 512 + lane32 * 8) ^ ((e & 7) << 4);
            uint2 pv; pv.x = pk2(v.x, v.y); pv.y = pk2(v.z, v.w);
            *(uint2*)((char*)sZ + byte0) = pv;
            int byte1 = (e * 512 + 256 + lane32 * 8) ^ ((e & 7) << 4);
            uint2 pu; pu.x = pk2(u.x, u.y); pu.y = pk2(u.z, u.w);
            *(uint2*)((char*)sZ + byte1) = pu;
        }
        __syncthreads();
        f32x4 acc[4] = {{0.f,0.f,0.f,0.f},{0.f,0.f,0.f,0.f},
                        {0.f,0.f,0.f,0.f},{0.f,0.f,0.f,0.f}};
        #pragma unroll
        for (int ks = 0; ks < 8; ++ks) {
            const int kb = (ks * 32 + lhi * 8) * 2;
            #pragma unroll
            for (int rt = 0; rt < 4; ++rt) {
                const int row = rt * 16 + l15;
                int byte = (row * 512 + kb) ^ ((row & 7) << 4);
                bhalf8 af = *(const bhalf8*)((const char*)sZ + byte);
                acc[rt] = __builtin_amdgcn_mfma_f32_16x16x32_bf16(af, bfrag[ks], acc[rt], 0, 0, 0);
            }
        }
        #pragma unroll
        for (int rt = 0; rt < 4; ++rt) {
            #pragma unroll
            for (int i = 0; i < 4; ++i) {
                float v = acc[rt][i] + b1v;
                v = fmaxf(v, 0.0f) * w2v;
                v += __shfl_xor(v, 1, 64);
                v += __shfl_xor(v, 2, 64);
                v += __shfl_xor(v, 4, 64);
                v += __shfl_xor(v, 8, 64);
                if (l15 == 0) sPart[wave][rt * 16 + lhi * 4 + i] = v;
            }
        }
        __syncthreads();
        if (tid < TE) {
            const int eg = base + tid;
            if (eg < E) {
                float s = b2v;
                #pragma unroll
                for (int w = 0; w < 8; ++w) s += sPart[w][tid];
                out[eg] = s;
            }
        }
    }
}

extern "C" void kernel_launch(void* const* d_in, const int* in_sizes, int n_in,
                              void* d_out, int out_size, void* d_ws, size_t ws_size,
                              hipStream_t stream) {
    const float* zd = (const float*)d_in[0];
    const float* zp = (const float*)d_in[1];
    const int*   eli = (const int*)d_in[2];
    const float* W1 = (const float*)d_in[3];
    const float* b1 = (const float*)d_in[4];
    const float* W2 = (const float*)d_in[5];
    const float* b2 = (const float*)d_in[6];
    float* out = (float*)d_out;

    const int E = in_sizes[2] / 2;
    const int nTiles = (E + TE - 1) / TE;
    const int nd = in_sizes[0];   // N_DRUG * 128 elements
    const int np = in_sizes[1];

    const size_t need = ((size_t)nd + (size_t)np) * sizeof(unsigned short);
    if (ws_size >= need) {
        unsigned short* zdb = (unsigned short*)d_ws;
        unsigned short* zpb = zdb + nd;
        const int na8 = nd / 8, nb8 = np / 8;
        const int cvtBlocks = (na8 + nb8 + 255) / 256;
        hipLaunchKernelGGL(cvt_kernel, dim3(cvtBlocks), dim3(256), 0, stream,
                           zd, zp, zdb, zpb, na8, nb8);
        hipLaunchKernelGGL(ec2_kernel, dim3(2048), dim3(512), 0, stream,
                           zdb, zpb, eli, W1, b1, W2, b2, out, E, nTiles);
    } else {
        hipLaunchKernelGGL(ec_fallback, dim3(2048), dim3(512), 0, stream,
                           zd, zp, eli, W1, b1, W2, b2, out, E, nTiles);
    }
}

// Round 3
// 96.250 us; speedup vs baseline: 4.3189x; 4.3189x over previous
//
#include <hip/hip_runtime.h>

// EdgeClassifier restructured:
//   Hd = zd @ W1[:, :128]^T + b1   (bf16, in ws)     [N_DRUG x 128]
//   Hp = zp @ W1[:, 128:]^T        (bf16, in ws)     [N_PROT x 128]
//   out[e] = W2 . relu(Hd[row[e]] + Hp[col[e]]) + b2
// 20x FLOP reduction vs per-edge GEMM; edge pass is a pure coalesced gather.

typedef __attribute__((ext_vector_type(8))) short bhalf8;
typedef __attribute__((ext_vector_type(4))) float f32x4;

__device__ __forceinline__ unsigned bfr(float f) {
    unsigned u = __builtin_bit_cast(unsigned, f);
    return (u + 0x7fffu + ((u >> 16) & 1u)) >> 16;
}
__device__ __forceinline__ unsigned pk2(float a, float b) {
    return bfr(a) | (bfr(b) << 16);
}
__device__ __forceinline__ float bl(unsigned u) {             // low bf16 -> f32
    return __builtin_bit_cast(float, u << 16);
}
__device__ __forceinline__ float bh(unsigned u) {             // high bf16 -> f32
    return __builtin_bit_cast(float, u & 0xffff0000u);
}

// ---------- pass A: H = z @ W1slice^T (+bias), bf16 out ----------
// one block = 64 rows, 512 threads / 8 waves, wave w owns output cols w*16..w*16+15
__global__ __launch_bounds__(512) void hprep_kernel(
    const float* __restrict__ z, const float* __restrict__ W1,
    const float* __restrict__ b1add,          // nullptr -> no bias
    unsigned short* __restrict__ H, int N, int koff)
{
    __shared__ __align__(16) short sZ[64 * 128];   // 16 KB bf16, XOR-swizzled
    const int tid  = threadIdx.x;
    const int wave = tid >> 6;
    const int lane = tid & 63;
    const int l15  = lane & 15;
    const int lhi  = lane >> 4;
    const int ocol = wave * 16 + l15;

    // B-fragments: lane holds W1[ocol][koff + ks*32 + lhi*8 + i]
    bhalf8 bfrag[4];
    #pragma unroll
    for (int ks = 0; ks < 4; ++ks) {
        const float4* src = (const float4*)(W1 + ocol * 256 + koff + ks * 32 + lhi * 8);
        float4 p = src[0], q = src[1];
        bhalf8 f;
        f[0] = (short)bfr(p.x); f[1] = (short)bfr(p.y);
        f[2] = (short)bfr(p.z); f[3] = (short)bfr(p.w);
        f[4] = (short)bfr(q.x); f[5] = (short)bfr(q.y);
        f[6] = (short)bfr(q.z); f[7] = (short)bfr(q.w);
        bfrag[ks] = f;
    }
    const float bias = b1add ? b1add[ocol] : 0.0f;

    const int r0 = blockIdx.x * 64;

    // stage 64 rows x 128 fp32 -> bf16 LDS (8 threads/row, 4 x float4 each)
    {
        const int rl = tid >> 3;
        const int grow = min(r0 + rl, N - 1);
        const float4* zr = (const float4*)(z + (size_t)grow * 128);
        #pragma unroll
        for (int q = 0; q < 4; ++q) {
            const int s = (tid & 7) + q * 8;     // 16B source chunk (4 floats)
            float4 v = zr[s];
            uint2 w; w.x = pk2(v.x, v.y); w.y = pk2(v.z, v.w);
            int byte = (rl * 256 + s * 8) ^ ((rl & 7) << 4);
            *(uint2*)((char*)sZ + byte) = w;
        }
    }
    __syncthreads();

    f32x4 acc[4] = {{0.f,0.f,0.f,0.f},{0.f,0.f,0.f,0.f},
                    {0.f,0.f,0.f,0.f},{0.f,0.f,0.f,0.f}};
    #pragma unroll
    for (int ks = 0; ks < 4; ++ks) {
        #pragma unroll
        for (int rt = 0; rt < 4; ++rt) {
            const int row = rt * 16 + l15;
            int byte = (row * 256 + ks * 64 + lhi * 16) ^ ((row & 7) << 4);
            bhalf8 af = *(const bhalf8*)((const char*)sZ + byte);
            acc[rt] = __builtin_amdgcn_mfma_f32_16x16x32_bf16(af, bfrag[ks], acc[rt], 0, 0, 0);
        }
    }
    #pragma unroll
    for (int rt = 0; rt < 4; ++rt) {
        #pragma unroll
        for (int i = 0; i < 4; ++i) {
            const int grow = r0 + rt * 16 + lhi * 4 + i;
            if (grow < N)
                H[(size_t)grow * 128 + ocol] = (unsigned short)bfr(acc[rt][i] + bias);
        }
    }
}

// ---------- pass B: per-edge gather + relu + dot(W2) ----------
// 16 lanes per edge, each lane owns an 8-element slice; 2 edges per group per iter
__global__ __launch_bounds__(256) void edge_kernel(
    const unsigned short* __restrict__ Hd, const unsigned short* __restrict__ Hp,
    const int* __restrict__ eli, const float* __restrict__ W2,
    const float* __restrict__ b2, float* __restrict__ out, int E)
{
    const int sub = threadIdx.x & 15;
    const int grp = threadIdx.x >> 4;          // 0..15
    float4 w2a = ((const float4*)W2)[sub * 2];
    float4 w2b = ((const float4*)W2)[sub * 2 + 1];
    const float b2v = b2[0];

    const int step = gridDim.x * 32;
    for (int base = blockIdx.x * 32; base < E; base += step) {
        #pragma unroll
        for (int u = 0; u < 2; ++u) {
            const int e = base + u * 16 + grp;
            if (e < E) {
                const int row = eli[e];
                const int col = eli[E + e];
                uint4 hd = ((const uint4*)(Hd + (size_t)row * 128))[sub];
                uint4 hp = ((const uint4*)(Hp + (size_t)col * 128))[sub];
                float s = 0.f;
                s = fmaf(fmaxf(bl(hd.x) + bl(hp.x), 0.f), w2a.x, s);
                s = fmaf(fmaxf(bh(hd.x) + bh(hp.x), 0.f), w2a.y, s);
                s = fmaf(fmaxf(bl(hd.y) + bl(hp.y), 0.f), w2a.z, s);
                s = fmaf(fmaxf(bh(hd.y) + bh(hp.y), 0.f), w2a.w, s);
                s = fmaf(fmaxf(bl(hd.z) + bl(hp.z), 0.f), w2b.x, s);
                s = fmaf(fmaxf(bh(hd.z) + bh(hp.z), 0.f), w2b.y, s);
                s = fmaf(fmaxf(bl(hd.w) + bl(hp.w), 0.f), w2b.z, s);
                s = fmaf(fmaxf(bh(hd.w) + bh(hp.w), 0.f), w2b.w, s);
                s += __shfl_xor(s, 1, 64);
                s += __shfl_xor(s, 2, 64);
                s += __shfl_xor(s, 4, 64);
                s += __shfl_xor(s, 8, 64);
                if (sub == 0) out[e] = s + b2v;
            }
        }
    }
}

// ---------- fallback: proven R1 kernel (fp32 gather, per-edge GEMM) ----------
#define TE 64
__global__ __launch_bounds__(512, 4) void ec_fallback(
    const float* __restrict__ zd, const float* __restrict__ zp,
    const int* __restrict__ eli, const float* __restrict__ W1,
    const float* __restrict__ b1, const float* __restrict__ W2,
    const float* __restrict__ b2, float* __restrict__ out,
    int E, int nTiles)
{
    __shared__ __align__(16) short sZ[TE * 256];
    __shared__ float sPart[8][TE];
    const int tid  = threadIdx.x;
    const int wave = tid >> 6;
    const int lane = tid & 63;
    const int l15  = lane & 15;
    const int lhi  = lane >> 4;
    const int ocol = wave * 16 + l15;
    bhalf8 bfrag[8];
    #pragma unroll
    for (int ks = 0; ks < 8; ++ks) {
        const float4* src = (const float4*)(W1 + ocol * 256 + ks * 32 + lhi * 8);
        float4 p = src[0], q = src[1];
        bhalf8 f;
        f[0] = (short)bfr(p.x); f[1] = (short)bfr(p.y);
        f[2] = (short)bfr(p.z); f[3] = (short)bfr(p.w);
        f[4] = (short)bfr(q.x); f[5] = (short)bfr(q.y);
        f[6] = (short)bfr(q.z); f[7] = (short)bfr(q.w);
        bfrag[ks] = f;
    }
    const float b1v = b1[ocol];
    const float w2v = W2[ocol];
    const float b2v = b2[0];
    const int slot = tid >> 5;
    const int lane32 = tid & 31;
    for (int tile = blockIdx.x; tile < nTiles; tile += gridDim.x) {
        const int base = tile * TE;
        __syncthreads();
        #pragma unroll
        for (int r = 0; r < 4; ++r) {
            const int e  = slot * 4 + r;
            const int eg = base + e;
            int drow = 0, pcol = 0;
            if (eg < E) { drow = eli[eg]; pcol = eli[E + eg]; }
            float4 v = ((const float4*)(zd + (size_t)drow * 128))[lane32];
            float4 u = ((const float4*)(zp + (size_t)pcol * 128))[lane32];
            int byte0 = (e * 512 + lane32 * 8) ^ ((e & 7) << 4);
            uint2 pv; pv.x = pk2(v.x, v.y); pv.y = pk2(v.z, v.w);
            *(uint2*)((char*)sZ + byte0) = pv;
            int byte1 = (e * 512 + 256 + lane32 * 8) ^ ((e & 7) << 4);
            uint2 pu; pu.x = pk2(u.x, u.y); pu.y = pk2(u.z, u.w);
            *(uint2*)((char*)sZ + byte1) = pu;
        }
        __syncthreads();
        f32x4 acc[4] = {{0.f,0.f,0.f,0.f},{0.f,0.f,0.f,0.f},
                        {0.f,0.f,0.f,0.f},{0.f,0.f,0.f,0.f}};
        #pragma unroll
        for (int ks = 0; ks < 8; ++ks) {
            const int kb = (ks * 32 + lhi * 8) * 2;
            #pragma unroll
            for (int rt = 0; rt < 4; ++rt) {
                const int row = rt * 16 + l15;
                int byte = (row * 512 + kb) ^ ((row & 7) << 4);
                bhalf8 af = *(const bhalf8*)((const char*)sZ + byte);
                acc[rt] = __builtin_amdgcn_mfma_f32_16x16x32_bf16(af, bfrag[ks], acc[rt], 0, 0, 0);
            }
        }
        #pragma unroll
        for (int rt = 0; rt < 4; ++rt) {
            #pragma unroll
            for (int i = 0; i < 4; ++i) {
                float v = acc[rt][i] + b1v;
                v = fmaxf(v, 0.0f) * w2v;
                v += __shfl_xor(v, 1, 64);
                v += __shfl_xor(v, 2, 64);
                v += __shfl_xor(v, 4, 64);
                v += __shfl_xor(v, 8, 64);
                if (l15 == 0) sPart[wave][rt * 16 + lhi * 4 + i] = v;
            }
        }
        __syncthreads();
        if (tid < TE) {
            const int eg = base + tid;
            if (eg < E) {
                float s = b2v;
                #pragma unroll
                for (int w = 0; w < 8; ++w) s += sPart[w][tid];
                out[eg] = s;
            }
        }
    }
}

extern "C" void kernel_launch(void* const* d_in, const int* in_sizes, int n_in,
                              void* d_out, int out_size, void* d_ws, size_t ws_size,
                              hipStream_t stream) {
    const float* zd = (const float*)d_in[0];
    const float* zp = (const float*)d_in[1];
    const int*   eli = (const int*)d_in[2];
    const float* W1 = (const float*)d_in[3];
    const float* b1 = (const float*)d_in[4];
    const float* W2 = (const float*)d_in[5];
    const float* b2 = (const float*)d_in[6];
    float* out = (float*)d_out;

    const int E  = in_sizes[2] / 2;
    const int nd = in_sizes[0];        // N_DRUG * 128
    const int np = in_sizes[1];        // N_PROT * 128

    const size_t need = ((size_t)nd + (size_t)np) * sizeof(unsigned short);
    if (ws_size >= need) {
        unsigned short* Hd = (unsigned short*)d_ws;
        unsigned short* Hp = Hd + nd;
        const int Nd = nd / 128, Np = np / 128;
        hipLaunchKernelGGL(hprep_kernel, dim3((Nd + 63) / 64), dim3(512), 0, stream,
                           zd, W1, b1, Hd, Nd, 0);
        hipLaunchKernelGGL(hprep_kernel, dim3((Np + 63) / 64), dim3(512), 0, stream,
                           zp, W1, (const float*)nullptr, Hp, Np, 128);
        hipLaunchKernelGGL(edge_kernel, dim3(4096), dim3(256), 0, stream,
                           Hd, Hp, eli, W2, b2, out, E);
    } else {
        const int nTiles = (E + TE - 1) / TE;
        hipLaunchKernelGGL(ec_fallback, dim3(2048), dim3(512), 0, stream,
                           zd, zp, eli, W1, b1, W2, b2, out, E, nTiles);
    }
}

// Round 4
// 89.538 us; speedup vs baseline: 4.6427x; 1.0750x over previous
//
#include <hip/hip_runtime.h>

// EdgeClassifier restructured:
//   Hd = zd @ W1[:, :128]^T + b1   (bf16, in ws)     [N_DRUG x 128]
//   Hp = zp @ W1[:, 128:]^T        (bf16, in ws)     [N_PROT x 128]
//   out[e] = W2 . relu(Hd[row[e]] + Hp[col[e]]) + b2
// R4: fused single hprep launch; edge pass deep-pipelined (4 edges/group,
// index prefetch one grid-stride ahead).

typedef __attribute__((ext_vector_type(8))) short bhalf8;
typedef __attribute__((ext_vector_type(4))) float f32x4;

__device__ __forceinline__ unsigned bfr(float f) {
    unsigned u = __builtin_bit_cast(unsigned, f);
    return (u + 0x7fffu + ((u >> 16) & 1u)) >> 16;
}
__device__ __forceinline__ unsigned pk2(float a, float b) {
    return bfr(a) | (bfr(b) << 16);
}
__device__ __forceinline__ float bl(unsigned u) { return __builtin_bit_cast(float, u << 16); }
__device__ __forceinline__ float bh(unsigned u) { return __builtin_bit_cast(float, u & 0xffff0000u); }

// ---------- pass A (fused): H = z @ W1slice^T (+bias), bf16 out ----------
// one block = 64 rows of one table; blocks [0,nbd) -> drug, [nbd,..) -> protein
__global__ __launch_bounds__(512) void hprep2_kernel(
    const float* __restrict__ zd, const float* __restrict__ zp,
    const float* __restrict__ W1, const float* __restrict__ b1,
    unsigned short* __restrict__ Hd, unsigned short* __restrict__ Hp,
    int Nd, int Np, int nbd)
{
    __shared__ __align__(16) short sZ[64 * 128];   // 16 KB bf16, XOR-swizzled
    const bool isP = blockIdx.x >= nbd;
    const float* z = isP ? zp : zd;
    unsigned short* H = isP ? Hp : Hd;
    const int N    = isP ? Np : Nd;
    const int koff = isP ? 128 : 0;
    const int blk  = isP ? blockIdx.x - nbd : blockIdx.x;

    const int tid  = threadIdx.x;
    const int wave = tid >> 6;
    const int lane = tid & 63;
    const int l15  = lane & 15;
    const int lhi  = lane >> 4;
    const int ocol = wave * 16 + l15;

    bhalf8 bfrag[4];
    #pragma unroll
    for (int ks = 0; ks < 4; ++ks) {
        const float4* src = (const float4*)(W1 + ocol * 256 + koff + ks * 32 + lhi * 8);
        float4 p = src[0], q = src[1];
        bhalf8 f;
        f[0] = (short)bfr(p.x); f[1] = (short)bfr(p.y);
        f[2] = (short)bfr(p.z); f[3] = (short)bfr(p.w);
        f[4] = (short)bfr(q.x); f[5] = (short)bfr(q.y);
        f[6] = (short)bfr(q.z); f[7] = (short)bfr(q.w);
        bfrag[ks] = f;
    }
    const float bias = isP ? 0.0f : b1[ocol];

    const int r0 = blk * 64;

    // stage 64 rows x 128 fp32 -> bf16 LDS (8 threads/row)
    {
        const int rl = tid >> 3;
        const int grow = min(r0 + rl, N - 1);
        const float4* zr = (const float4*)(z + (size_t)grow * 128);
        #pragma unroll
        for (int q = 0; q < 4; ++q) {
            const int s = (tid & 7) + q * 8;
            float4 v = zr[s];
            uint2 w; w.x = pk2(v.x, v.y); w.y = pk2(v.z, v.w);
            int byte = (rl * 256 + s * 8) ^ ((rl & 7) << 4);
            *(uint2*)((char*)sZ + byte) = w;
        }
    }
    __syncthreads();

    f32x4 acc[4] = {{0.f,0.f,0.f,0.f},{0.f,0.f,0.f,0.f},
                    {0.f,0.f,0.f,0.f},{0.f,0.f,0.f,0.f}};
    #pragma unroll
    for (int ks = 0; ks < 4; ++ks) {
        #pragma unroll
        for (int rt = 0; rt < 4; ++rt) {
            const int row = rt * 16 + l15;
            int byte = (row * 256 + ks * 64 + lhi * 16) ^ ((row & 7) << 4);
            bhalf8 af = *(const bhalf8*)((const char*)sZ + byte);
            acc[rt] = __builtin_amdgcn_mfma_f32_16x16x32_bf16(af, bfrag[ks], acc[rt], 0, 0, 0);
        }
    }
    #pragma unroll
    for (int rt = 0; rt < 4; ++rt) {
        #pragma unroll
        for (int i = 0; i < 4; ++i) {
            const int grow = r0 + rt * 16 + lhi * 4 + i;
            if (grow < N)
                H[(size_t)grow * 128 + ocol] = (unsigned short)bfr(acc[rt][i] + bias);
        }
    }
}

// ---------- pass B: per-edge gather + relu + dot(W2) ----------
// 16 lanes/edge; 4 edges per group per iter (8 uint4 gathers in flight/lane);
// indices prefetched one grid-stride ahead.
__global__ __launch_bounds__(256) void edge_kernel(
    const unsigned short* __restrict__ Hd, const unsigned short* __restrict__ Hp,
    const int* __restrict__ eli, const float* __restrict__ W2,
    const float* __restrict__ b2, float* __restrict__ out, int E)
{
    const int sub = threadIdx.x & 15;
    const int grp = threadIdx.x >> 4;          // 0..15
    float4 w2a = ((const float4*)W2)[sub * 2];
    float4 w2b = ((const float4*)W2)[sub * 2 + 1];
    const float b2v = b2[0];

    const int step = gridDim.x * 64;
    int base = blockIdx.x * 64;
    if (base >= E) return;

    int row[4], col[4];
    #pragma unroll
    for (int u = 0; u < 4; ++u) {
        const int e = base + u * 16 + grp;
        row[u] = (e < E) ? eli[e] : 0;
        col[u] = (e < E) ? eli[E + e] : 0;
    }

    for (; base < E; base += step) {
        // issue 8 gathers for the current 4 edges
        uint4 hd[4], hp[4];
        #pragma unroll
        for (int u = 0; u < 4; ++u) {
            hd[u] = ((const uint4*)(Hd + (size_t)row[u] * 128))[sub];
            hp[u] = ((const uint4*)(Hp + (size_t)col[u] * 128))[sub];
        }
        // prefetch next iteration's indices while gathers are in flight
        const int nb = base + step;
        if (nb < E) {
            #pragma unroll
            for (int u = 0; u < 4; ++u) {
                const int e = nb + u * 16 + grp;
                row[u] = (e < E) ? eli[e] : 0;
                col[u] = (e < E) ? eli[E + e] : 0;
            }
        }
        #pragma unroll
        for (int u = 0; u < 4; ++u) {
            float s = 0.f;
            s = fmaf(fmaxf(bl(hd[u].x) + bl(hp[u].x), 0.f), w2a.x, s);
            s = fmaf(fmaxf(bh(hd[u].x) + bh(hp[u].x), 0.f), w2a.y, s);
            s = fmaf(fmaxf(bl(hd[u].y) + bl(hp[u].y), 0.f), w2a.z, s);
            s = fmaf(fmaxf(bh(hd[u].y) + bh(hp[u].y), 0.f), w2a.w, s);
            s = fmaf(fmaxf(bl(hd[u].z) + bl(hp[u].z), 0.f), w2b.x, s);
            s = fmaf(fmaxf(bh(hd[u].z) + bh(hp[u].z), 0.f), w2b.y, s);
            s = fmaf(fmaxf(bl(hd[u].w) + bl(hp[u].w), 0.f), w2b.z, s);
            s = fmaf(fmaxf(bh(hd[u].w) + bh(hp[u].w), 0.f), w2b.w, s);
            s += __shfl_xor(s, 1, 64);
            s += __shfl_xor(s, 2, 64);
            s += __shfl_xor(s, 4, 64);
            s += __shfl_xor(s, 8, 64);
            const int e = base + u * 16 + grp;
            if (sub == 0 && e < E) out[e] = s + b2v;
        }
    }
}

// ---------- fallback: proven R1 kernel (fp32 gather, per-edge GEMM) ----------
#define TE 64
__global__ __launch_bounds__(512, 4) void ec_fallback(
    const float* __restrict__ zd, const float* __restrict__ zp,
    const int* __restrict__ eli, const float* __restrict__ W1,
    const float* __restrict__ b1, const float* __restrict__ W2,
    const float* __restrict__ b2, float* __restrict__ out,
    int E, int nTiles)
{
    __shared__ __align__(16) short sZ[TE * 256];
    __shared__ float sPart[8][TE];
    const int tid  = threadIdx.x;
    const int wave = tid >> 6;
    const int lane = tid & 63;
    const int l15  = lane & 15;
    const int lhi  = lane >> 4;
    const int ocol = wave * 16 + l15;
    bhalf8 bfrag[8];
    #pragma unroll
    for (int ks = 0; ks < 8; ++ks) {
        const float4* src = (const float4*)(W1 + ocol * 256 + ks * 32 + lhi * 8);
        float4 p = src[0], q = src[1];
        bhalf8 f;
        f[0] = (short)bfr(p.x); f[1] = (short)bfr(p.y);
        f[2] = (short)bfr(p.z); f[3] = (short)bfr(p.w);
        f[4] = (short)bfr(q.x); f[5] = (short)bfr(q.y);
        f[6] = (short)bfr(q.z); f[7] = (short)bfr(q.w);
        bfrag[ks] = f;
    }
    const float b1v = b1[ocol];
    const float w2v = W2[ocol];
    const float b2v = b2[0];
    const int slot = tid >> 5;
    const int lane32 = tid & 31;
    for (int tile = blockIdx.x; tile < nTiles; tile += gridDim.x) {
        const int base = tile * TE;
        __syncthreads();
        #pragma unroll
        for (int r = 0; r < 4; ++r) {
            const int e  = slot * 4 + r;
            const int eg = base + e;
            int drow = 0, pcol = 0;
            if (eg < E) { drow = eli[eg]; pcol = eli[E + eg]; }
            float4 v = ((const float4*)(zd + (size_t)drow * 128))[lane32];
            float4 u = ((const float4*)(zp + (size_t)pcol * 128))[lane32];
            int byte0 = (e * 512 + lane32 * 8) ^ ((e & 7) << 4);
            uint2 pv; pv.x = pk2(v.x, v.y); pv.y = pk2(v.z, v.w);
            *(uint2*)((char*)sZ + byte0) = pv;
            int byte1 = (e * 512 + 256 + lane32 * 8) ^ ((e & 7) << 4);
            uint2 pu; pu.x = pk2(u.x, u.y); pu.y = pk2(u.z, u.w);
            *(uint2*)((char*)sZ + byte1) = pu;
        }
        __syncthreads();
        f32x4 acc[4] = {{0.f,0.f,0.f,0.f},{0.f,0.f,0.f,0.f},
                        {0.f,0.f,0.f,0.f},{0.f,0.f,0.f,0.f}};
        #pragma unroll
        for (int ks = 0; ks < 8; ++ks) {
            const int kb = (ks * 32 + lhi * 8) * 2;
            #pragma unroll
            for (int rt = 0; rt < 4; ++rt) {
                const int row = rt * 16 + l15;
                int byte = (row * 512 + kb) ^ ((row & 7) << 4);
                bhalf8 af = *(const bhalf8*)((const char*)sZ + byte);
                acc[rt] = __builtin_amdgcn_mfma_f32_16x16x32_bf16(af, bfrag[ks], acc[rt], 0, 0, 0);
            }
        }
        #pragma unroll
        for (int rt = 0; rt < 4; ++rt) {
            #pragma unroll
            for (int i = 0; i < 4; ++i) {
                float v = acc[rt][i] + b1v;
                v = fmaxf(v, 0.0f) * w2v;
                v += __shfl_xor(v, 1, 64);
                v += __shfl_xor(v, 2, 64);
                v += __shfl_xor(v, 4, 64);
                v += __shfl_xor(v, 8, 64);
                if (l15 == 0) sPart[wave][rt * 16 + lhi * 4 + i] = v;
            }
        }
        __syncthreads();
        if (tid < TE) {
            const int eg = base + tid;
            if (eg < E) {
                float s = b2v;
                #pragma unroll
                for (int w = 0; w < 8; ++w) s += sPart[w][tid];
                out[eg] = s;
            }
        }
    }
}

extern "C" void kernel_launch(void* const* d_in, const int* in_sizes, int n_in,
                              void* d_out, int out_size, void* d_ws, size_t ws_size,
                              hipStream_t stream) {
    const float* zd = (const float*)d_in[0];
    const float* zp = (const float*)d_in[1];
    const int*   eli = (const int*)d_in[2];
    const float* W1 = (const float*)d_in[3];
    const float* b1 = (const float*)d_in[4];
    const float* W2 = (const float*)d_in[5];
    const float* b2 = (const float*)d_in[6];
    float* out = (float*)d_out;

    const int E  = in_sizes[2] / 2;
    const int nd = in_sizes[0];        // N_DRUG * 128
    const int np = in_sizes[1];        // N_PROT * 128

    const size_t need = ((size_t)nd + (size_t)np) * sizeof(unsigned short);
    if (ws_size >= need) {
        unsigned short* Hd = (unsigned short*)d_ws;
        unsigned short* Hp = Hd + nd;
        const int Nd = nd / 128, Np = np / 128;
        const int nbd = (Nd + 63) / 64, nbp = (Np + 63) / 64;
        hipLaunchKernelGGL(hprep2_kernel, dim3(nbd + nbp), dim3(512), 0, stream,
                           zd, zp, W1, b1, Hd, Hp, Nd, Np, nbd);
        hipLaunchKernelGGL(edge_kernel, dim3(2048), dim3(256), 0, stream,
                           Hd, Hp, eli, W2, b2, out, E);
    } else {
        const int nTiles = (E + TE - 1) / TE;
        hipLaunchKernelGGL(ec_fallback, dim3(2048), dim3(512), 0, stream,
                           zd, zp, eli, W1, b1, W2, b2, out, E, nTiles);
    }
}